// Round 17
// baseline (2630.948 us; speedup 1.0000x reference)
//
#include <hip/hip_runtime.h>
#include <hip/hip_cooperative_groups.h>
#include <math.h>

namespace cg = cooperative_groups;

#define B_  256
#define T_  48
#define D_  89
#define H_  128
#define C_  64
#define NH_ 8
#define HD_ 8
#define N2T 96   // 2*T

// output layout (floats)
#define XIMP_OFF 0
#define LOSS_OFF 1093632
#define HID_OFF  1093633
#define Y_OFF    2666497
#define YS_OFF   2666753

typedef unsigned int uint_t;
typedef _Float16 h2_t __attribute__((ext_vector_type(2)));

__device__ __forceinline__ float wave_sum64(float v) {
    v += __shfl_xor(v, 32);
    v += __shfl_xor(v, 16);
    v += __shfl_xor(v, 8);
    v += __shfl_xor(v, 4);
    v += __shfl_xor(v, 2);
    v += __shfl_xor(v, 1);
    return v;
}

__device__ __forceinline__ uint_t packh2(float lo, float hi) {
    union { h2_t h; uint_t u; } c;
    c.h.x = (_Float16)lo;
    c.h.y = (_Float16)hi;
    return c.u;
}
__device__ __forceinline__ h2_t as_h2(uint_t u) {
    union { uint_t u; h2_t h; } c;
    c.u = u;
    return c.h;
}
__device__ __forceinline__ float dot2h(uint_t w, uint_t a, float acc) {
#if __has_builtin(__builtin_amdgcn_fdot2)
    return __builtin_amdgcn_fdot2(as_h2(w), as_h2(a), acc, false);
#else
    h2_t hw = as_h2(w), ha = as_h2(a);
    return fmaf((float)hw.y, (float)ha.y, fmaf((float)hw.x, (float)ha.x, acc));
#endif
}
__device__ __forceinline__ float sigm(float v) { return 1.f / (1.f + __expf(-v)); }

#define DOT96H(W, A, acc) do { \
    _Pragma("unroll") \
    for (int it_ = 0; it_ < 3; ++it_) { \
        int idx_ = jj + 8 * it_; \
        uint2 w_ = ((const uint2*)(W))[idx_]; \
        uint2 a_ = ((const uint2*)(A))[idx_]; \
        acc = dot2h(w_.x, a_.x, acc); \
        acc = dot2h(w_.y, a_.y, acc); \
    } } while (0)

#define DOT128H(W, A, acc) do { \
    _Pragma("unroll") \
    for (int it_ = 0; it_ < 4; ++it_) { \
        int idx_ = jj + 8 * it_; \
        uint2 w_ = ((const uint2*)(W))[idx_]; \
        uint2 a_ = ((const uint2*)(A))[idx_]; \
        acc = dot2h(w_.x, a_.x, acc); \
        acc = dot2h(w_.y, a_.y, acc); \
    } } while (0)

// ---------------- merged prep (f32 transposes) + pack (f16x2 scan weights)
__device__ __forceinline__ void tr_f32(const float* __restrict__ s, float* __restrict__ d,
                                       int li, int R, int C) {
    int r = li / C, c = li - r * C;
    d[c * R + r] = s[li];
}

__global__ void k_wprep(const float* W_wo, const float* W_inp, const float* ain_w,
                        const float* aout_w, const float* ff1_w, const float* ff2_w,
                        const float* W_op1,
                        float* W_woT, float* W_inpT, float* ain_T,
                        float* aout_T, float* ff1_T, float* ff2_T, float* op1_T,
                        const float* __restrict__ W_dh, const float* __restrict__ W_hist,
                        const float* __restrict__ W_ih, const float* __restrict__ W_hh,
                        uint_t* __restrict__ wdh_h, uint_t* __restrict__ whist_h,
                        uint_t* __restrict__ wihx_h, uint_t* __restrict__ wihm_h,
                        uint_t* __restrict__ whh_h) {
    int i = blockIdx.x * 256 + threadIdx.x;
    if (i < 7921)         tr_f32(W_wo,   W_woT,  i,          89, 89);
    else if (i < 13617)   tr_f32(W_inp,  W_inpT, i - 7921,   64, 89);
    else if (i < 25905)   tr_f32(ain_w,  ain_T,  i - 13617, 192, 64);
    else if (i < 30001)   tr_f32(aout_w, aout_T, i - 25905,  64, 64);
    else if (i < 34097)   tr_f32(ff1_w,  ff1_T,  i - 30001,  64, 64);
    else if (i < 38193)   tr_f32(ff2_w,  ff2_T,  i - 34097,  64, 64);
    else if (i < 46385)   tr_f32(W_op1,  op1_T,  i - 38193, 128, 64);
    else {
        int p = i - 46385;
        if (p < 6144) {
            int r = p / 48, c = p - r * 48;
            const float* src = W_dh + r * 89;
            float lo = (c < 45) ? src[2 * c] : 0.f;
            float hi = (c < 44) ? src[2 * c + 1] : 0.f;
            wdh_h[p] = packh2(lo, hi);
        } else if (p < 11840) {
            int j = p - 6144;
            int r = j / 64, c = j - r * 64;
            const float* src = W_hist + r * 128;
            whist_h[j] = packh2(src[2 * c], src[2 * c + 1]);
        } else if (p < 30272) {
            int j = p - 11840;
            int r = j / 48, c = j - r * 48;
            const float* src = W_ih + (size_t)r * 178;
            float lo = (c < 45) ? src[2 * c] : 0.f;
            float hi = (c < 44) ? src[2 * c + 1] : 0.f;
            wihx_h[j] = packh2(lo, hi);
        } else if (p < 48704) {
            int j = p - 30272;
            int r = j / 48, c = j - r * 48;
            const float* src = W_ih + (size_t)r * 178 + 89;
            float lo = (c < 45) ? src[2 * c] : 0.f;
            float hi = (c < 44) ? src[2 * c + 1] : 0.f;
            wihm_h[j] = packh2(lo, hi);
        } else if (p < 73280) {
            int j = p - 48704;
            int r = j / 64, c = j - r * 64;
            const float* src = W_hh + (size_t)r * 128;
            whh_h[j] = packh2(src[2 * c], src[2 * c + 1]);
        }
    }
}

// ---------------- fused: phaseA+qkv -> gridsync -> attn+den -> gridsync
//                  -> transform+reduce_h0 (val,h0 in LDS) -> scan
struct FusedP {
    const float *x, *mask, *deltas, *last_obs, *medians;
    const float *W_woT, *b_wo, *W_inpT, *b_inp, *ain_T, *ain_b;
    const float *aout_T, *aout_b, *ln1_g, *ln1_b, *ff1_T, *ff1_b;
    const float *ff2_T, *ff2_b, *ln2_g, *ln2_b, *op1_T, *b_op1;
    const float *W_op2, *b_op2;
    const uint_t *wdh_h, *whist_h, *wihx_h, *wihm_h, *whh_h;
    const float *b_dh, *W_dx, *b_dx, *b_hist, *W_feat, *b_feat, *W_wc, *b_wc;
    const float *b_ih, *b_hh, *W_cls, *b_cls;
    float *data, *qb, *kb, *vb, *attnO, *out, *num_part, *den_part;
};

__global__ __launch_bounds__(1024) void k_fused(FusedP p) {
    int b = blockIdx.x;
    int tid = threadIdx.x;
    __shared__ __align__(16) char smem[83072];
    __shared__ float h0_s[H_];
    float* sf = (float*)smem;
    uint_t* su = (uint_t*)smem;

    // ============ Phase A + qkv: 8 subgroups x 128 threads, 6 iters ============
    {
        int sg = tid >> 7;
        int stid = tid & 127;
        float* dd  = sf + sg * 96;
        float* lo  = sf + 768 + sg * 96;
        float* dec = sf + 1536 + sg * 96;
        float* rows = sf + 2304 + sg * 128;
        for (int it6 = 0; it6 < 6; ++it6) {
            int t = it6 * 8 + sg;
            int base = (b * T_ + t) * D_;
            if (stid < D_) {
                float dv = p.deltas[base + stid] - p.medians[stid];
                dd[stid] = dv;
                lo[stid] = p.last_obs[base + stid];
            }
            __syncthreads();
            if (stid < D_) {
                float a0 = p.b_wo[stid], a1 = 0.f;
                for (int j = 0; j < 88; j += 2) {
                    a0 = fmaf(dd[j],     p.W_woT[j * D_ + stid],       a0);
                    a1 = fmaf(dd[j + 1], p.W_woT[(j + 1) * D_ + stid], a1);
                }
                float acc = fmaf(dd[88], p.W_woT[88 * D_ + stid], a0) + a1;
                float dv = dd[stid];
                float s = (dv > 0.f) ? 1.f : ((dv < 0.f) ? -1.f : 0.f);
                dec[stid] = 0.5f * (1.f - tanhf(s * fabsf(acc)));
            }
            __syncthreads();
            {
                int c = stid & 63;
                int half = stid >> 6;
                const float* src = half ? dec : lo;
                float a0 = p.b_inp[c], a1 = 0.f;
                for (int j = 0; j < 88; j += 2) {
                    a0 = fmaf(src[j],     p.W_inpT[j * C_ + c],       a0);
                    a1 = fmaf(src[j + 1], p.W_inpT[(j + 1) * C_ + c], a1);
                }
                float acc = fmaf(src[88], p.W_inpT[88 * C_ + c], a0) + a1;
                int i = c >> 1;
                float div = __expf((float)i * -0.28782313662425574f);
                float ang = (float)t * div;
                float pe = (c & 1) ? cosf(ang) : sinf(ang);
                float val = acc + pe;
                rows[half * 64 + c] = val;
                p.data[((b * N2T) + half * T_ + t) * C_ + c] = val;
            }
            __syncthreads();
            #pragma unroll
            for (int it = 0; it < 3; ++it) {
                int idx = it * 128 + stid;
                int h2 = idx / 192;
                int col = idx - h2 * 192;
                const float* row = rows + h2 * 64;
                float a0 = p.ain_b[col], a1 = 0.f;
                #pragma unroll
                for (int j = 0; j < 64; j += 2) {
                    a0 = fmaf(row[j],     p.ain_T[j * 192 + col],       a0);
                    a1 = fmaf(row[j + 1], p.ain_T[(j + 1) * 192 + col], a1);
                }
                float acc = a0 + a1;
                int n = h2 * T_ + t;
                int part = col >> 6;
                int cc = col & 63;
                int hh = cc >> 3, d = cc & 7;
                float* dst = (part == 0) ? p.qb : ((part == 1) ? p.kb : p.vb);
                dst[(((n * NH_ + hh) * B_ + b) * HD_) + d] = acc;
            }
            __syncthreads();
        }
    }
    cg::this_grid().sync();

    // ============ attention (3 units/block) + den (wave group 3) ============
    {
        int g = tid >> 8;
        int ut = tid & 255;
        const float scale = 0.35355339059327373f;
        float q[HD_];
        float* k_l = sf + g * 4608;
        float* v_l = k_l + 2304;
        if (g < 3) {
            int unit = b * 3 + g;
            size_t base = ((size_t)unit * B_ + ut) * HD_;
            #pragma unroll
            for (int d = 0; d < HD_; ++d) q[d] = p.qb[base + d] * scale;
            #pragma unroll
            for (int d = 0; d < HD_; ++d) {
                k_l[ut * 9 + d] = p.kb[base + d];
                v_l[ut * 9 + d] = p.vb[base + d];
            }
        } else {
            int w = (tid - 768) >> 6;
            int lane = tid & 63;
            for (int t = w; t < T_; t += 4) {
                const float* mrow = p.mask + (b * T_ + t) * D_;
                float s = (lane < 89 ? mrow[lane] : 0.f) +
                          (lane + 64 < 89 ? mrow[lane + 64] : 0.f);
                s = wave_sum64(s);
                if (lane == 0) p.den_part[b * T_ + t] = s;
            }
        }
        __syncthreads();
        if (g < 3) {
            int unit = b * 3 + g;
            int n = unit >> 3, h = unit & 7;
            float mx = -1e30f;
            #pragma unroll 4
            for (int t = 0; t < B_; ++t) {
                float sc = 0.f;
                #pragma unroll
                for (int d = 0; d < HD_; ++d) sc = fmaf(q[d], k_l[t * 9 + d], sc);
                mx = fmaxf(mx, sc);
            }
            float l = 0.f;
            float acc[HD_] = {0.f, 0.f, 0.f, 0.f, 0.f, 0.f, 0.f, 0.f};
            #pragma unroll 2
            for (int t = 0; t < B_; ++t) {
                float sc = 0.f;
                #pragma unroll
                for (int d = 0; d < HD_; ++d) sc = fmaf(q[d], k_l[t * 9 + d], sc);
                float pe = __expf(sc - mx);
                l += pe;
                #pragma unroll
                for (int d = 0; d < HD_; ++d) acc[d] = fmaf(pe, v_l[t * 9 + d], acc[d]);
            }
            float inv = 1.f / l;
            float* op = p.attnO + ((size_t)ut * N2T + n) * C_ + h * HD_;
            #pragma unroll
            for (int d = 0; d < HD_; ++d) op[d] = acc[d] * inv;
        }
    }
    cg::this_grid().sync();

    // ============ transform (16 subgroups x 64) + reduce_h0 (val,h0 in LDS) ============
    {
        int sg = tid >> 6;
        int c = tid & 63;
        float* arr = sf + sg * 256;
        float* orow = arr;
        float* x1s = arr + 64;
        float* hbuf = arr + 128;
        float* x2s = arr + 192;
        float* val_l = sf + 4096;      // 96*128 floats
        for (int it6 = 0; it6 < 6; ++it6) {
            int nrow = it6 * 16 + sg;
            int bn = b * 96 + nrow;
            float d0 = p.data[bn * C_ + c];
            orow[c] = p.attnO[bn * C_ + c];
            __syncthreads();
            float a0 = p.aout_b[c], a1 = 0.f;
            #pragma unroll
            for (int j = 0; j < C_; j += 2) {
                a0 = fmaf(orow[j],     p.aout_T[j * C_ + c],       a0);
                a1 = fmaf(orow[j + 1], p.aout_T[(j + 1) * C_ + c], a1);
            }
            float r = d0 + a0 + a1;
            float mean = wave_sum64(r) * (1.f / 64.f);
            float df = r - mean;
            float var = wave_sum64(df * df) * (1.f / 64.f);
            float x1 = df * rsqrtf(var + 1e-5f) * p.ln1_g[c] + p.ln1_b[c];
            x1s[c] = x1;
            __syncthreads();
            a0 = p.ff1_b[c]; a1 = 0.f;
            #pragma unroll
            for (int j = 0; j < C_; j += 2) {
                a0 = fmaf(x1s[j],     p.ff1_T[j * C_ + c],       a0);
                a1 = fmaf(x1s[j + 1], p.ff1_T[(j + 1) * C_ + c], a1);
            }
            float accf = a0 + a1;
            float ge = 0.5f * accf * (1.f + erff(accf * 0.7071067811865475f));
            hbuf[c] = ge;
            __syncthreads();
            a0 = p.ff2_b[c]; a1 = 0.f;
            #pragma unroll
            for (int j = 0; j < C_; j += 2) {
                a0 = fmaf(hbuf[j],     p.ff2_T[j * C_ + c],       a0);
                a1 = fmaf(hbuf[j + 1], p.ff2_T[(j + 1) * C_ + c], a1);
            }
            float r2 = x1 + a0 + a1;
            float mean2 = wave_sum64(r2) * (1.f / 64.f);
            float df2 = r2 - mean2;
            float var2 = wave_sum64(df2 * df2) * (1.f / 64.f);
            float x2 = df2 * rsqrtf(var2 + 1e-5f) * p.ln2_g[c] + p.ln2_b[c];
            x2s[c] = x2;
            __syncthreads();
            #pragma unroll
            for (int rep = 0; rep < 2; ++rep) {
                int k = c + rep * 64;
                float b0 = p.b_op1[k], b1 = 0.f;
                #pragma unroll
                for (int j = 0; j < C_; j += 2) {
                    b0 = fmaf(x2s[j],     p.op1_T[j * H_ + k],       b0);
                    b1 = fmaf(x2s[j + 1], p.op1_T[(j + 1) * H_ + k], b1);
                }
                val_l[nrow * 128 + k] = b0 + b1;
            }
            __syncthreads();
        }
        if (tid < 128) {
            float a0 = p.b_op2[0], a1 = 0.f;
            for (int n = 0; n < N2T; n += 2) {
                a0 = fmaf(val_l[n * 128 + tid],       p.W_op2[n],     a0);
                a1 = fmaf(val_l[(n + 1) * 128 + tid], p.W_op2[n + 1], a1);
            }
            h0_s[tid] = a0 + a1;
        }
    }
    __syncthreads();

    // ============ scan (round-16 4-phase; smem re-carved) ============
    {
        int wave = tid >> 6;
        int lane = tid & 63;
        int oo = lane >> 3;
        int jj = lane & 7;

        uint_t* wwcg_l  = su;
        uint_t* wwcm_l  = su + 4272;
        uint_t* wfeat_l = su + 8544;
        uint_t* wdh_l   = su + 12816;     // 128*49
        float*  h_s     = sf + 19088;
        uint_t* h_h     = su + 19216;
        float*  xt_s    = sf + 19280;
        float*  m_s     = sf + 19376;
        float*  xh_s    = sf + 19472;
        float*  beta_s  = sf + 19568;
        float*  diff_s  = sf + 19664;
        uint_t* dt_h    = su + 19760;
        uint_t* gx_h    = su + 19808;
        uint_t* m_h     = su + 19856;
        uint_t* xr_h    = su + 19904;
        uint_t* ximp_h  = su + 19952;
        float*  gis     = sf + 20000;
        float*  ghs     = sf + 20384;

        float dxw = 0.f, dxb = 0.f;
        if (tid >= 768 && tid < 857) {
            int o = tid - 768;
            dxw = p.W_dx[o * 90];
            dxb = p.b_dx[o];
        }
        float h0v = 0.f;
        if (tid < 128) h0v = h0_s[tid];
        __syncthreads();   // h0_s read done; smem can be overwritten

        for (int i = tid; i < 89 * 48; i += 1024) {
            int r = i / 48, c = i - r * 48;
            const float* wr = p.W_wc + (size_t)r * 178;
            float lo = (c < 45) ? wr[2 * c] : 0.f;
            float hi = (c < 44) ? wr[2 * c + 1] : 0.f;
            wwcg_l[i] = packh2(lo, hi);
            const float* wm = wr + 89;
            float lo2 = (c < 45) ? wm[2 * c] : 0.f;
            float hi2 = (c < 44) ? wm[2 * c + 1] : 0.f;
            wwcm_l[i] = packh2(lo2, hi2);
            const float* wf = p.W_feat + r * 89;
            float lo3 = (c < 45 && 2 * c != r) ? wf[2 * c] : 0.f;
            float hi3 = (c < 44 && 2 * c + 1 != r) ? wf[2 * c + 1] : 0.f;
            wfeat_l[i] = packh2(lo3, hi3);
        }
        for (int i = tid; i < 128 * 45; i += 1024) {
            int r = i / 45, c = i - r * 45;
            wdh_l[r * 49 + c] = p.wdh_h[r * 48 + c];
        }
        if (tid == 500) {
            #pragma unroll
            for (int k = 45; k < 48; ++k) {
                dt_h[k] = 0u; gx_h[k] = 0u; m_h[k] = 0u; xr_h[k] = 0u; ximp_h[k] = 0u;
            }
        }
        {
            int nb = b * T_ * D_;
            if (tid >= 128 && tid < 217) xt_s[tid - 128] = p.x[nb + tid - 128];
            else if (tid >= 256 && tid < 345) {
                int o = tid - 256;
                float mv = p.mask[nb + o];
                m_s[o] = mv;
                float nx = __shfl_down(mv, 1);
                if (o + 1 >= 89) nx = 0.f;
                if ((o & 1) == 0) m_h[o >> 1] = packh2(mv, nx);
            } else if (tid >= 768 && tid < 857) {
                int o = tid - 768;
                float dv = p.deltas[nb + o];
                float gxv = __expf(-fmaxf(dv * dxw + dxb, 0.f));
                float nd = __shfl_down(dv, 1);
                float ng = __shfl_down(gxv, 1);
                if (o + 1 >= 89) { nd = 0.f; ng = 0.f; }
                if ((o & 1) == 0) { dt_h[o >> 1] = packh2(dv, nd); gx_h[o >> 1] = packh2(gxv, ng); }
            }
        }
        __syncthreads();
        if (tid < 128) {
            const uint_t* wr = wdh_l + tid * 49;
            float acc = 0.f;
            #pragma unroll
            for (int j = 0; j < 45; ++j) acc = dot2h(wr[j], dt_h[j], acc);
            float hd = h0v * __expf(-fmaxf(acc + p.b_dh[tid], 0.f));
            h_s[tid] = hd;
            float nx = __shfl_down(hd, 1);
            if ((tid & 1) == 0) h_h[tid >> 1] = packh2(hd, nx);
        }
        __syncthreads();

        for (int t = 0; t < T_; ++t) {
            for (int c = wave; c < 120; c += 16) {
                if (c < 12) {
                    int o = c * 8 + oo;
                    int ro = (o < 89) ? o : 88;
                    float acc = 0.f;
                    DOT96H(wwcg_l + ro * 48, gx_h, acc);
                    DOT96H(wwcm_l + ro * 48, m_h, acc);
                    acc += __shfl_xor(acc, 1); acc += __shfl_xor(acc, 2); acc += __shfl_xor(acc, 4);
                    if (jj == 0 && o < 89) beta_s[o] = acc + p.b_wc[o];
                } else if (c < 60) {
                    int o = (c - 12) * 8 + oo;
                    float acc = 0.f;
                    DOT96H(p.wihm_h + o * 48, m_h, acc);
                    acc += __shfl_xor(acc, 1); acc += __shfl_xor(acc, 2); acc += __shfl_xor(acc, 4);
                    if (jj == 0) gis[o] = acc + p.b_ih[o];
                } else if (c < 72) {
                    int o = (c - 60) * 8 + oo;
                    int ro = (o < 89) ? o : 88;
                    float acc = 0.f;
                    DOT128H(p.whist_h + ro * 64, h_h, acc);
                    acc += __shfl_xor(acc, 1); acc += __shfl_xor(acc, 2); acc += __shfl_xor(acc, 4);
                    if (jj == 0) {
                        float xh = acc + p.b_hist[ro];
                        float m = m_s[ro];
                        float xrv = m * xt_s[ro] + (1.f - m) * xh;
                        float nx = __shfl_down(xrv, 8);
                        if (o + 1 >= 89) nx = 0.f;
                        if (o < 89) xh_s[o] = xh;
                        if ((oo & 1) == 0 && o < 89) xr_h[o >> 1] = packh2(xrv, nx);
                    }
                } else {
                    int o = (c - 72) * 8 + oo;
                    float acc = 0.f;
                    DOT128H(p.whh_h + o * 64, h_h, acc);
                    acc += __shfl_xor(acc, 1); acc += __shfl_xor(acc, 2); acc += __shfl_xor(acc, 4);
                    if (jj == 0) ghs[o] = acc + p.b_hh[o];
                }
            }
            __syncthreads();
            if (wave < 12) {
                int c = wave;
                int o = c * 8 + oo;
                int ro = (o < 89) ? o : 88;
                float xu = 0.f;
                DOT96H(wfeat_l + ro * 48, xr_h, xu);
                xu += __shfl_xor(xu, 1); xu += __shfl_xor(xu, 2); xu += __shfl_xor(xu, 4);
                if (jj == 0) {
                    float xuf = xu + p.b_feat[ro];
                    float btf = beta_s[ro];
                    float xc = btf * xuf + (1.f - btf) * xh_s[ro];
                    float m = m_s[ro];
                    float xtv = xt_s[ro];
                    float xi = m * xtv + (1.f - m) * xc;
                    float nx = __shfl_down(xi, 8);
                    if (o + 1 >= 89) nx = 0.f;
                    if (o < 89) {
                        p.out[XIMP_OFF + (b * T_ + t) * D_ + o] = xi;
                        diff_s[o] = fabsf(xtv - xc) * m;
                    }
                    if ((oo & 1) == 0 && o < 89) ximp_h[o >> 1] = packh2(xi, nx);
                }
            } else if (tid >= 768 && tid < 857 && t + 1 < T_) {
                int o = tid - 768;
                float dv = p.deltas[(b * T_ + t + 1) * D_ + o];
                float gxv = __expf(-fmaxf(dv * dxw + dxb, 0.f));
                float nd = __shfl_down(dv, 1);
                float ng = __shfl_down(gxv, 1);
                if (o + 1 >= 89) { nd = 0.f; ng = 0.f; }
                if ((o & 1) == 0) { dt_h[o >> 1] = packh2(dv, nd); gx_h[o >> 1] = packh2(gxv, ng); }
            }
            __syncthreads();
            for (int c = wave; c < 48; c += 16) {
                int o = c * 8 + oo;
                float acc = 0.f;
                DOT96H(p.wihx_h + o * 48, ximp_h, acc);
                acc += __shfl_xor(acc, 1); acc += __shfl_xor(acc, 2); acc += __shfl_xor(acc, 4);
                if (jj == 0) gis[o] += acc;
            }
            __syncthreads();
            if (tid < 128) {
                float r = sigm(gis[tid] + ghs[tid]);
                float z = sigm(gis[128 + tid] + ghs[128 + tid]);
                float g = tanhf(gis[256 + tid] + r * ghs[256 + tid]);
                float hn = (1.f - z) * g + z * h_s[tid];
                p.out[HID_OFF + (size_t)(b * T_ + t) * H_ + tid] = hn;
                float hd = hn;
                if (t + 1 < T_) {
                    const uint_t* wr = wdh_l + tid * 49;
                    float acc = 0.f;
                    #pragma unroll
                    for (int j = 0; j < 45; ++j) acc = dot2h(wr[j], dt_h[j], acc);
                    hd = hn * __expf(-fmaxf(acc + p.b_dh[tid], 0.f));
                }
                h_s[tid] = hd;
                float nx = __shfl_down(hd, 1);
                if ((tid & 1) == 0) h_h[tid >> 1] = packh2(hd, nx);
            } else if (tid >= 960) {
                int l = tid - 960;
                float s = diff_s[l] + ((l < 25) ? diff_s[64 + l] : 0.f);
                s = wave_sum64(s);
                if (l == 0) p.num_part[t * B_ + b] = s;
            } else if (t + 1 < T_) {
                int nb = (b * T_ + t + 1) * D_;
                if (tid < 217) xt_s[tid - 128] = p.x[nb + tid - 128];
                else if (tid >= 256 && tid < 345) {
                    int o = tid - 256;
                    float mv = p.mask[nb + o];
                    m_s[o] = mv;
                    float nx = __shfl_down(mv, 1);
                    if (o + 1 >= 89) nx = 0.f;
                    if ((o & 1) == 0) m_h[o >> 1] = packh2(mv, nx);
                }
            }
            __syncthreads();
        }
        if (tid < 64) {
            float pcl = h_s[tid] * p.W_cls[tid] + h_s[tid + 64] * p.W_cls[tid + 64];
            pcl = wave_sum64(pcl);
            if (tid == 0) {
                float y = pcl + p.b_cls[0];
                p.out[Y_OFF + b] = y;
                p.out[YS_OFF + b] = 1.f / (1.f + __expf(-y));
            }
        }
    }
}

// ---------------- final loss reduction (num + den partials)
__global__ void k_loss(const float* __restrict__ num_part, const float* __restrict__ den_part,
                       float* __restrict__ out) {
    int tid = threadIdx.x;
    float v = 0.f;
    if (tid < T_) {
        float s = 0.f, dn = 0.f;
        for (int b = 0; b < B_; ++b) {
            s += num_part[tid * B_ + b];
            dn += den_part[b * T_ + tid];
        }
        v = s / (dn + 1e-5f);
    }
    v = wave_sum64(v);
    if (tid == 0) out[LOSS_OFF] = v;
}

extern "C" void kernel_launch(void* const* d_in, const int* in_sizes, int n_in,
                              void* d_out, int out_size, void* d_ws, size_t ws_size,
                              hipStream_t stream) {
    const float* x        = (const float*)d_in[0];
    const float* mask     = (const float*)d_in[1];
    const float* deltas   = (const float*)d_in[2];
    const float* last_obs = (const float*)d_in[3];
    const float* medians  = (const float*)d_in[4];
    const float* W_dh  = (const float*)d_in[5];
    const float* b_dh  = (const float*)d_in[6];
    const float* W_dx  = (const float*)d_in[7];
    const float* b_dx  = (const float*)d_in[8];
    const float* W_hist= (const float*)d_in[9];
    const float* b_hist= (const float*)d_in[10];
    const float* W_feat= (const float*)d_in[11];
    const float* b_feat= (const float*)d_in[12];
    const float* W_wc  = (const float*)d_in[13];
    const float* b_wc  = (const float*)d_in[14];
    const float* W_wo  = (const float*)d_in[15];
    const float* b_wo  = (const float*)d_in[16];
    const float* W_cls = (const float*)d_in[17];
    const float* b_cls = (const float*)d_in[18];
    const float* W_ih  = (const float*)d_in[19];
    const float* W_hh  = (const float*)d_in[20];
    const float* b_ih  = (const float*)d_in[21];
    const float* b_hh  = (const float*)d_in[22];
    const float* W_inp = (const float*)d_in[23];
    const float* b_inp = (const float*)d_in[24];
    const float* W_op1 = (const float*)d_in[25];
    const float* b_op1 = (const float*)d_in[26];
    const float* W_op2 = (const float*)d_in[27];
    const float* b_op2 = (const float*)d_in[28];
    const float* attn_in_w  = (const float*)d_in[29];
    const float* attn_in_b  = (const float*)d_in[30];
    const float* attn_out_w = (const float*)d_in[31];
    const float* attn_out_b = (const float*)d_in[32];
    const float* ln1_g = (const float*)d_in[33];
    const float* ln1_b = (const float*)d_in[34];
    const float* ln2_g = (const float*)d_in[35];
    const float* ln2_b = (const float*)d_in[36];
    const float* ff1_w = (const float*)d_in[37];
    const float* ff1_b = (const float*)d_in[38];
    const float* ff2_w = (const float*)d_in[39];
    const float* ff2_b = (const float*)d_in[40];

    float* out = (float*)d_out;
    float* ws = (float*)d_ws;

    float* data  = ws;                                   // B*96*64
    float* qb    = data  + (size_t)B_ * N2T * C_;
    float* kb    = qb    + (size_t)N2T * NH_ * B_ * HD_;
    float* vb    = kb    + (size_t)N2T * NH_ * B_ * HD_;
    float* attnO = vb    + (size_t)N2T * NH_ * B_ * HD_;
    float* nump  = attnO + (size_t)B_ * N2T * C_;
    float* denp  = nump  + T_ * B_;
    float* W_woT = denp  + B_ * T_;
    float* W_inpT= W_woT + 7921;
    float* ain_T = W_inpT + 5696;
    float* aout_T= ain_T + 12288;
    float* ff1_T = aout_T + 4096;
    float* ff2_T = ff1_T + 4096;
    float* op1_T = ff2_T + 4096;
    uint_t* wdh_h   = (uint_t*)(op1_T + 8192);
    uint_t* whist_h = wdh_h + 6144;
    uint_t* wihx_h  = whist_h + 5696;
    uint_t* wihm_h  = wihx_h + 18432;
    uint_t* whh_h   = wihm_h + 18432;

    k_wprep<<<468, 256, 0, stream>>>(W_wo, W_inp, attn_in_w, attn_out_w, ff1_w, ff2_w, W_op1,
                                     W_woT, W_inpT, ain_T, aout_T, ff1_T, ff2_T, op1_T,
                                     W_dh, W_hist, W_ih, W_hh,
                                     wdh_h, whist_h, wihx_h, wihm_h, whh_h);

    FusedP fp;
    fp.x = x; fp.mask = mask; fp.deltas = deltas; fp.last_obs = last_obs; fp.medians = medians;
    fp.W_woT = W_woT; fp.b_wo = b_wo; fp.W_inpT = W_inpT; fp.b_inp = b_inp;
    fp.ain_T = ain_T; fp.ain_b = attn_in_b;
    fp.aout_T = aout_T; fp.aout_b = attn_out_b;
    fp.ln1_g = ln1_g; fp.ln1_b = ln1_b;
    fp.ff1_T = ff1_T; fp.ff1_b = ff1_b; fp.ff2_T = ff2_T; fp.ff2_b = ff2_b;
    fp.ln2_g = ln2_g; fp.ln2_b = ln2_b;
    fp.op1_T = op1_T; fp.b_op1 = b_op1; fp.W_op2 = W_op2; fp.b_op2 = b_op2;
    fp.wdh_h = wdh_h; fp.whist_h = whist_h; fp.wihx_h = wihx_h; fp.wihm_h = wihm_h; fp.whh_h = whh_h;
    fp.b_dh = b_dh; fp.W_dx = W_dx; fp.b_dx = b_dx; fp.b_hist = b_hist;
    fp.W_feat = W_feat; fp.b_feat = b_feat; fp.W_wc = W_wc; fp.b_wc = b_wc;
    fp.b_ih = b_ih; fp.b_hh = b_hh; fp.W_cls = W_cls; fp.b_cls = b_cls;
    fp.data = data; fp.qb = qb; fp.kb = kb; fp.vb = vb; fp.attnO = attnO;
    fp.out = out; fp.num_part = nump; fp.den_part = denp;

    void* kargs[] = { (void*)&fp };
    hipLaunchCooperativeKernel((const void*)k_fused, dim3(B_), dim3(1024), kargs, 0, stream);

    k_loss<<<1, 64, 0, stream>>>(nump, denp, out);
}

// Round 18
// 587.387 us; speedup vs baseline: 4.4791x; 4.4791x over previous
//
#include <hip/hip_runtime.h>
#include <math.h>

#define B_  256
#define T_  48
#define D_  89
#define H_  128
#define C_  64
#define NH_ 8
#define HD_ 8
#define N2T 96   // 2*T

// output layout (floats)
#define XIMP_OFF 0
#define LOSS_OFF 1093632
#define HID_OFF  1093633
#define Y_OFF    2666497
#define YS_OFF   2666753

typedef unsigned int uint_t;
typedef _Float16 h2_t __attribute__((ext_vector_type(2)));

__device__ __forceinline__ float wave_sum64(float v) {
    v += __shfl_xor(v, 32);
    v += __shfl_xor(v, 16);
    v += __shfl_xor(v, 8);
    v += __shfl_xor(v, 4);
    v += __shfl_xor(v, 2);
    v += __shfl_xor(v, 1);
    return v;
}

__device__ __forceinline__ uint_t packh2(float lo, float hi) {
    union { h2_t h; uint_t u; } c;
    c.h.x = (_Float16)lo;
    c.h.y = (_Float16)hi;
    return c.u;
}
__device__ __forceinline__ h2_t as_h2(uint_t u) {
    union { uint_t u; h2_t h; } c;
    c.u = u;
    return c.h;
}
// 2-MAC f16 dot with BOTH operands packed f16
__device__ __forceinline__ float dot2h(uint_t w, uint_t a, float acc) {
#if __has_builtin(__builtin_amdgcn_fdot2)
    return __builtin_amdgcn_fdot2(as_h2(w), as_h2(a), acc, false);
#else
    h2_t hw = as_h2(w), ha = as_h2(a);
    return fmaf((float)hw.y, (float)ha.y, fmaf((float)hw.x, (float)ha.x, acc));
#endif
}
__device__ __forceinline__ float sigm(float v) { return 1.f / (1.f + __expf(-v)); }

// K=96 dot: 24 uint2 pairs (weights + packed activations), 8 j-slices
#define DOT96H(W, A, acc) do { \
    _Pragma("unroll") \
    for (int it_ = 0; it_ < 3; ++it_) { \
        int idx_ = jj + 8 * it_; \
        uint2 w_ = ((const uint2*)(W))[idx_]; \
        uint2 a_ = ((const uint2*)(A))[idx_]; \
        acc = dot2h(w_.x, a_.x, acc); \
        acc = dot2h(w_.y, a_.y, acc); \
    } } while (0)

// K=128 dot: 32 uint2 pairs
#define DOT128H(W, A, acc) do { \
    _Pragma("unroll") \
    for (int it_ = 0; it_ < 4; ++it_) { \
        int idx_ = jj + 8 * it_; \
        uint2 w_ = ((const uint2*)(W))[idx_]; \
        uint2 a_ = ((const uint2*)(A))[idx_]; \
        acc = dot2h(w_.x, a_.x, acc); \
        acc = dot2h(w_.y, a_.y, acc); \
    } } while (0)

// ---------------- merged prep (f32 transposes) + pack (f16x2 scan weights)
__device__ __forceinline__ void tr_f32(const float* __restrict__ s, float* __restrict__ d,
                                       int li, int R, int C) {
    int r = li / C, c = li - r * C;
    d[c * R + r] = s[li];
}

__global__ void k_wprep(const float* W_wo, const float* W_inp, const float* ain_w,
                        const float* aout_w, const float* ff1_w, const float* ff2_w,
                        const float* W_op1,
                        float* W_woT, float* W_inpT, float* ain_T,
                        float* aout_T, float* ff1_T, float* ff2_T, float* op1_T,
                        const float* __restrict__ W_dh, const float* __restrict__ W_hist,
                        const float* __restrict__ W_ih, const float* __restrict__ W_hh,
                        uint_t* __restrict__ wdh_h, uint_t* __restrict__ whist_h,
                        uint_t* __restrict__ wihx_h, uint_t* __restrict__ wihm_h,
                        uint_t* __restrict__ whh_h) {
    int i = blockIdx.x * 256 + threadIdx.x;
    if (i < 7921)         tr_f32(W_wo,   W_woT,  i,          89, 89);
    else if (i < 13617)   tr_f32(W_inp,  W_inpT, i - 7921,   64, 89);
    else if (i < 25905)   tr_f32(ain_w,  ain_T,  i - 13617, 192, 64);
    else if (i < 30001)   tr_f32(aout_w, aout_T, i - 25905,  64, 64);
    else if (i < 34097)   tr_f32(ff1_w,  ff1_T,  i - 30001,  64, 64);
    else if (i < 38193)   tr_f32(ff2_w,  ff2_T,  i - 34097,  64, 64);
    else if (i < 46385)   tr_f32(W_op1,  op1_T,  i - 38193, 128, 64);
    else {
        int p = i - 46385;
        if (p < 6144) {                        // W_dh: 128 x 48 (K=89 pad 96)
            int r = p / 48, c = p - r * 48;
            const float* src = W_dh + r * 89;
            float lo = (c < 45) ? src[2 * c] : 0.f;
            float hi = (c < 44) ? src[2 * c + 1] : 0.f;
            wdh_h[p] = packh2(lo, hi);
        } else if (p < 11840) {                // W_hist: 89 x 64 (K=128)
            int j = p - 6144;
            int r = j / 64, c = j - r * 64;
            const float* src = W_hist + r * 128;
            whist_h[j] = packh2(src[2 * c], src[2 * c + 1]);
        } else if (p < 30272) {                // W_ih x-part: 384 x 48
            int j = p - 11840;
            int r = j / 48, c = j - r * 48;
            const float* src = W_ih + (size_t)r * 178;
            float lo = (c < 45) ? src[2 * c] : 0.f;
            float hi = (c < 44) ? src[2 * c + 1] : 0.f;
            wihx_h[j] = packh2(lo, hi);
        } else if (p < 48704) {                // W_ih m-part: 384 x 48
            int j = p - 30272;
            int r = j / 48, c = j - r * 48;
            const float* src = W_ih + (size_t)r * 178 + 89;
            float lo = (c < 45) ? src[2 * c] : 0.f;
            float hi = (c < 44) ? src[2 * c + 1] : 0.f;
            wihm_h[j] = packh2(lo, hi);
        } else if (p < 73280) {                // W_hh: 384 x 64
            int j = p - 48704;
            int r = j / 64, c = j - r * 64;
            const float* src = W_hh + (size_t)r * 128;
            whh_h[j] = packh2(src[2 * c], src[2 * c + 1]);
        }
    }
}

// ---------------- Phase A fused with qkv: one block per (b,t); 128 threads.
__global__ void k_phaseA(const float* __restrict__ last_obs,
                         const float* __restrict__ deltas,
                         const float* __restrict__ medians,
                         const float* __restrict__ W_woT, const float* __restrict__ b_wo,
                         const float* __restrict__ W_inpT, const float* __restrict__ b_inp,
                         const float* __restrict__ ain_T, const float* __restrict__ ain_b,
                         float* __restrict__ data,
                         float* __restrict__ qb, float* __restrict__ kb, float* __restrict__ vb) {
    int bt = blockIdx.x;
    int b = bt / T_;
    int t = bt - b * T_;
    __shared__ float dd[D_], lo[D_], dec[D_];
    __shared__ float rows[2][C_];
    int tid = threadIdx.x;
    int base = (b * T_ + t) * D_;
    if (tid < D_) {
        float dv = deltas[base + tid] - medians[tid];
        dd[tid] = dv;
        lo[tid] = last_obs[base + tid];
    }
    __syncthreads();
    if (tid < D_) {
        float a0 = b_wo[tid], a1 = 0.f;
        for (int j = 0; j < 88; j += 2) {
            a0 = fmaf(dd[j],     W_woT[j * D_ + tid],       a0);
            a1 = fmaf(dd[j + 1], W_woT[(j + 1) * D_ + tid], a1);
        }
        float acc = fmaf(dd[88], W_woT[88 * D_ + tid], a0) + a1;
        float dv = dd[tid];
        float s = (dv > 0.f) ? 1.f : ((dv < 0.f) ? -1.f : 0.f);
        dec[tid] = 0.5f * (1.f - tanhf(s * fabsf(acc)));
    }
    __syncthreads();
    int c = tid & 63;
    int half = tid >> 6;
    {
        const float* src = half ? dec : lo;
        float a0 = b_inp[c], a1 = 0.f;
        for (int j = 0; j < 88; j += 2) {
            a0 = fmaf(src[j],     W_inpT[j * C_ + c],       a0);
            a1 = fmaf(src[j + 1], W_inpT[(j + 1) * C_ + c], a1);
        }
        float acc = fmaf(src[88], W_inpT[88 * C_ + c], a0) + a1;
        int i = c >> 1;
        float div = __expf((float)i * -0.28782313662425574f);
        float ang = (float)t * div;
        float pe = (c & 1) ? cosf(ang) : sinf(ang);
        float val = acc + pe;
        rows[half][c] = val;
        data[((b * N2T) + half * T_ + t) * C_ + c] = val;
    }
    __syncthreads();
    #pragma unroll
    for (int it = 0; it < 3; ++it) {
        int idx = it * 128 + tid;
        int h2 = idx / 192;
        int col = idx - h2 * 192;
        const float* row = rows[h2];
        float a0 = ain_b[col], a1 = 0.f;
        #pragma unroll
        for (int j = 0; j < 64; j += 2) {
            a0 = fmaf(row[j],     ain_T[j * 192 + col],       a0);
            a1 = fmaf(row[j + 1], ain_T[(j + 1) * 192 + col], a1);
        }
        float acc = a0 + a1;
        int n = h2 * T_ + t;
        int part = col >> 6;
        int cc = col & 63;
        int hh = cc >> 3, d = cc & 7;
        float* dst = (part == 0) ? qb : ((part == 1) ? kb : vb);
        dst[(((n * NH_ + hh) * B_ + b) * HD_) + d] = acc;
    }
}

// ---------------- attention: one block per (n,h); 256 threads.
__global__ void k_attn(const float* __restrict__ qb, const float* __restrict__ kb,
                       const float* __restrict__ vb, float* __restrict__ attnO) {
    int n = blockIdx.x >> 3;
    int h = blockIdx.x & 7;
    __shared__ float k_lds[B_][HD_ + 1];
    __shared__ float v_lds[B_][HD_ + 1];
    int s = threadIdx.x;
    const float scale = 0.35355339059327373f;
    size_t base = ((size_t)blockIdx.x * B_ + s) * HD_;
    float q[HD_];
    #pragma unroll
    for (int d = 0; d < HD_; ++d) q[d] = qb[base + d] * scale;
    #pragma unroll
    for (int d = 0; d < HD_; ++d) { k_lds[s][d] = kb[base + d]; v_lds[s][d] = vb[base + d]; }
    __syncthreads();
    float m = -1e30f;
    #pragma unroll 4
    for (int t = 0; t < B_; ++t) {
        float sc = 0.f;
        #pragma unroll
        for (int d = 0; d < HD_; ++d) sc = fmaf(q[d], k_lds[t][d], sc);
        m = fmaxf(m, sc);
    }
    float l = 0.f;
    float acc[HD_] = {0.f, 0.f, 0.f, 0.f, 0.f, 0.f, 0.f, 0.f};
    #pragma unroll 2
    for (int t = 0; t < B_; ++t) {
        float sc = 0.f;
        #pragma unroll
        for (int d = 0; d < HD_; ++d) sc = fmaf(q[d], k_lds[t][d], sc);
        float p = __expf(sc - m);
        l += p;
        #pragma unroll
        for (int d = 0; d < HD_; ++d) acc[d] = fmaf(p, v_lds[t][d], acc[d]);
    }
    float inv = 1.f / l;
    float* op = attnO + ((size_t)s * N2T + n) * C_ + h * HD_;
    #pragma unroll
    for (int d = 0; d < HD_; ++d) op[d] = acc[d] * inv;
}

// ---------------- transformer post-attn (2-accumulator dots)
__global__ void k_transform(const float* __restrict__ data,
                            const float* __restrict__ attnO,
                            const float* __restrict__ aout_T, const float* __restrict__ aout_b,
                            const float* __restrict__ ln1_g, const float* __restrict__ ln1_b,
                            const float* __restrict__ ff1_T, const float* __restrict__ ff1_b,
                            const float* __restrict__ ff2_T, const float* __restrict__ ff2_b,
                            const float* __restrict__ ln2_g, const float* __restrict__ ln2_b,
                            const float* __restrict__ op1_T, const float* __restrict__ b_op1,
                            float* __restrict__ val) {
    int bn = blockIdx.x;
    __shared__ float orow[C_], x1s[C_], hbuf[C_], x2s[C_];
    int c = threadIdx.x;
    float d0 = data[bn * C_ + c];
    orow[c] = attnO[bn * C_ + c];
    __syncthreads();
    float a0 = aout_b[c], a1 = 0.f;
    #pragma unroll
    for (int j = 0; j < C_; j += 2) {
        a0 = fmaf(orow[j],     aout_T[j * C_ + c],       a0);
        a1 = fmaf(orow[j + 1], aout_T[(j + 1) * C_ + c], a1);
    }
    float r = d0 + a0 + a1;
    float mean = wave_sum64(r) * (1.f / 64.f);
    float df = r - mean;
    float var = wave_sum64(df * df) * (1.f / 64.f);
    float x1 = df * rsqrtf(var + 1e-5f) * ln1_g[c] + ln1_b[c];
    x1s[c] = x1;
    __syncthreads();
    a0 = ff1_b[c]; a1 = 0.f;
    #pragma unroll
    for (int j = 0; j < C_; j += 2) {
        a0 = fmaf(x1s[j],     ff1_T[j * C_ + c],       a0);
        a1 = fmaf(x1s[j + 1], ff1_T[(j + 1) * C_ + c], a1);
    }
    float accf = a0 + a1;
    float ge = 0.5f * accf * (1.f + erff(accf * 0.7071067811865475f));
    hbuf[c] = ge;
    __syncthreads();
    a0 = ff2_b[c]; a1 = 0.f;
    #pragma unroll
    for (int j = 0; j < C_; j += 2) {
        a0 = fmaf(hbuf[j],     ff2_T[j * C_ + c],       a0);
        a1 = fmaf(hbuf[j + 1], ff2_T[(j + 1) * C_ + c], a1);
    }
    float r2 = x1 + a0 + a1;
    float mean2 = wave_sum64(r2) * (1.f / 64.f);
    float df2 = r2 - mean2;
    float var2 = wave_sum64(df2 * df2) * (1.f / 64.f);
    float x2 = df2 * rsqrtf(var2 + 1e-5f) * ln2_g[c] + ln2_b[c];
    x2s[c] = x2;
    __syncthreads();
    #pragma unroll
    for (int rep = 0; rep < 2; ++rep) {
        int k = c + rep * 64;
        float b0 = b_op1[k], b1 = 0.f;
        #pragma unroll
        for (int j = 0; j < C_; j += 2) {
            b0 = fmaf(x2s[j],     op1_T[j * H_ + k],       b0);
            b1 = fmaf(x2s[j + 1], op1_T[(j + 1) * H_ + k], b1);
        }
        val[(size_t)bn * H_ + k] = b0 + b1;
    }
}

// ---------------- h0 reduce
__global__ void k_reduce_h0(const float* __restrict__ val,
                            const float* __restrict__ W_op2, const float* __restrict__ b_op2,
                            float* __restrict__ h0) {
    int b = blockIdx.x;
    int h = threadIdx.x;
    float a0 = b_op2[0], a1 = 0.f;
    for (int n = 0; n < N2T; n += 2) {
        a0 = fmaf(val[((size_t)b * N2T + n) * H_ + h],       W_op2[n],     a0);
        a1 = fmaf(val[((size_t)b * N2T + n + 1) * H_ + h],   W_op2[n + 1], a1);
    }
    h0[b * H_ + h] = a0 + a1;
}

// ---------------- per-step mask denominator
__global__ void k_den(const float* __restrict__ mask, float* __restrict__ den) {
    int t = blockIdx.x;
    int tid = threadIdx.x;
    float s = 0.f;
    const int total = B_ * D_;
    for (int i = tid; i < total; i += 256) {
        int b = i / D_;
        int d = i - b * D_;
        s += mask[(b * T_ + t) * D_ + d];
    }
    s = wave_sum64(s);
    __shared__ float red[4];
    if ((tid & 63) == 0) red[tid >> 6] = s;
    __syncthreads();
    if (tid == 0) den[t] = red[0] + red[1] + red[2] + red[3];
}

// ---------------- recurrent scan: 256 blocks x 1024 threads (16 waves).
// 4-phase structure: PA(beta|gi_m|x_h|gh) -> P3(xu+combine | dt/gx prefetch)
// -> P4(gi_x) -> P5(GRU+gamma+hdec | xt/m prefetch | loss).
__global__ __launch_bounds__(1024)
void k_scan(const float* __restrict__ x, const float* __restrict__ mask,
            const float* __restrict__ deltas,
            const uint_t* __restrict__ wdh_h, const float* __restrict__ b_dh,
            const float* __restrict__ W_dx, const float* __restrict__ b_dx,
            const uint_t* __restrict__ whist_h, const float* __restrict__ b_hist,
            const float* __restrict__ W_feat, const float* __restrict__ b_feat,
            const float* __restrict__ W_wc, const float* __restrict__ b_wc,
            const uint_t* __restrict__ wihx_h, const uint_t* __restrict__ wihm_h,
            const uint_t* __restrict__ whh_h,
            const float* __restrict__ b_ih, const float* __restrict__ b_hh,
            const float* __restrict__ W_cls, const float* __restrict__ b_cls,
            const float* __restrict__ h0,
            float* __restrict__ out, float* __restrict__ num_part) {
    int b = blockIdx.x;
    int tid = threadIdx.x;
    int wave = tid >> 6;
    int lane = tid & 63;
    int oo = lane >> 3;       // row within chunk
    int jj = lane & 7;        // j-slice

    __shared__ __align__(16) float h_s[H_];
    __shared__ __align__(16) uint_t h_h[64];
    __shared__ __align__(16) float xt_s[96], m_s[96], xh_s[96], beta_s[96], diff_s[96];
    __shared__ __align__(16) uint_t dt_h[48], gx_h[48], m_h[48], xr_h[48], ximp_h[48];
    __shared__ __align__(16) float gis[384], ghs[384];
    __shared__ __align__(16) uint_t wwcg_l[89 * 48];
    __shared__ __align__(16) uint_t wwcm_l[89 * 48];
    __shared__ __align__(16) uint_t wfeat_l[89 * 48];
    __shared__ __align__(16) uint_t wdh_l[128 * 49];   // stride 49: 2-way banks (free)

    float dxw = 0.f, dxb = 0.f;
    if (tid >= 768 && tid < 857) {
        int o = tid - 768;
        dxw = W_dx[o * 90];
        dxb = b_dx[o];
    }

    for (int i = tid; i < 89 * 48; i += 1024) {
        int r = i / 48, c = i - r * 48;
        const float* wr = W_wc + (size_t)r * 178;
        float lo = (c < 45) ? wr[2 * c] : 0.f;
        float hi = (c < 44) ? wr[2 * c + 1] : 0.f;
        wwcg_l[i] = packh2(lo, hi);
        const float* wm = wr + 89;
        float lo2 = (c < 45) ? wm[2 * c] : 0.f;
        float hi2 = (c < 44) ? wm[2 * c + 1] : 0.f;
        wwcm_l[i] = packh2(lo2, hi2);
        const float* wf = W_feat + r * 89;
        float lo3 = (c < 45 && 2 * c != r) ? wf[2 * c] : 0.f;
        float hi3 = (c < 44 && 2 * c + 1 != r) ? wf[2 * c + 1] : 0.f;
        wfeat_l[i] = packh2(lo3, hi3);
    }
    for (int i = tid; i < 128 * 45; i += 1024) {
        int r = i / 45, c = i - r * 45;
        wdh_l[r * 49 + c] = wdh_h[r * 48 + c];
    }
    if (tid == 500) {
        #pragma unroll
        for (int k = 45; k < 48; ++k) {
            dt_h[k] = 0u; gx_h[k] = 0u; m_h[k] = 0u; xr_h[k] = 0u; ximp_h[k] = 0u;
        }
    }
    float h0v = 0.f;
    if (tid < 128) h0v = h0[b * H_ + tid];
    {
        int nb = b * T_ * D_;
        if (tid >= 128 && tid < 217) xt_s[tid - 128] = x[nb + tid - 128];
        else if (tid >= 256 && tid < 345) {
            int o = tid - 256;
            float mv = mask[nb + o];
            m_s[o] = mv;
            float nx = __shfl_down(mv, 1);
            if (o + 1 >= 89) nx = 0.f;
            if ((o & 1) == 0) m_h[o >> 1] = packh2(mv, nx);
        } else if (tid >= 768 && tid < 857) {
            int o = tid - 768;
            float dv = deltas[nb + o];
            float gxv = __expf(-fmaxf(dv * dxw + dxb, 0.f));
            float nd = __shfl_down(dv, 1);
            float ng = __shfl_down(gxv, 1);
            if (o + 1 >= 89) { nd = 0.f; ng = 0.f; }
            if ((o & 1) == 0) { dt_h[o >> 1] = packh2(dv, nd); gx_h[o >> 1] = packh2(gxv, ng); }
        }
    }
    __syncthreads();
    // prologue gamma(0): hdec(0) = h0 * exp(-relu(W_dh . dt(0)))
    if (tid < 128) {
        const uint_t* wr = wdh_l + tid * 49;
        float acc = 0.f;
        #pragma unroll
        for (int j = 0; j < 45; ++j) acc = dot2h(wr[j], dt_h[j], acc);
        float hd = h0v * __expf(-fmaxf(acc + b_dh[tid], 0.f));
        h_s[tid] = hd;
        float nx = __shfl_down(hd, 1);
        if ((tid & 1) == 0) h_h[tid >> 1] = packh2(hd, nx);
    }
    __syncthreads();

    for (int t = 0; t < T_; ++t) {
        // ---- PA: beta(12) | gi_m(48) | x_h(12) | gh(48) = 120 chunks
        for (int c = wave; c < 120; c += 16) {
            if (c < 12) {
                int o = c * 8 + oo;
                int ro = (o < 89) ? o : 88;
                float acc = 0.f;
                DOT96H(wwcg_l + ro * 48, gx_h, acc);
                DOT96H(wwcm_l + ro * 48, m_h, acc);
                acc += __shfl_xor(acc, 1); acc += __shfl_xor(acc, 2); acc += __shfl_xor(acc, 4);
                if (jj == 0 && o < 89) beta_s[o] = acc + b_wc[o];
            } else if (c < 60) {
                int o = (c - 12) * 8 + oo;
                float acc = 0.f;
                DOT96H(wihm_h + o * 48, m_h, acc);
                acc += __shfl_xor(acc, 1); acc += __shfl_xor(acc, 2); acc += __shfl_xor(acc, 4);
                if (jj == 0) gis[o] = acc + b_ih[o];
            } else if (c < 72) {
                int o = (c - 60) * 8 + oo;
                int ro = (o < 89) ? o : 88;
                float acc = 0.f;
                DOT128H(whist_h + ro * 64, h_h, acc);
                acc += __shfl_xor(acc, 1); acc += __shfl_xor(acc, 2); acc += __shfl_xor(acc, 4);
                if (jj == 0) {
                    float xh = acc + b_hist[ro];
                    float m = m_s[ro];
                    float xrv = m * xt_s[ro] + (1.f - m) * xh;
                    float nx = __shfl_down(xrv, 8);
                    if (o + 1 >= 89) nx = 0.f;
                    if (o < 89) xh_s[o] = xh;
                    if ((oo & 1) == 0 && o < 89) xr_h[o >> 1] = packh2(xrv, nx);
                }
            } else {
                int o = (c - 72) * 8 + oo;
                float acc = 0.f;
                DOT128H(whh_h + o * 64, h_h, acc);
                acc += __shfl_xor(acc, 1); acc += __shfl_xor(acc, 2); acc += __shfl_xor(acc, 4);
                if (jj == 0) ghs[o] = acc + b_hh[o];
            }
        }
        __syncthreads();
        // ---- P3: xu(12 chunks)+combine  |  dt/gx(t+1) prefetch
        if (wave < 12) {
            int c = wave;
            int o = c * 8 + oo;
            int ro = (o < 89) ? o : 88;
            float xu = 0.f;
            DOT96H(wfeat_l + ro * 48, xr_h, xu);
            xu += __shfl_xor(xu, 1); xu += __shfl_xor(xu, 2); xu += __shfl_xor(xu, 4);
            if (jj == 0) {
                float xuf = xu + b_feat[ro];
                float btf = beta_s[ro];
                float xc = btf * xuf + (1.f - btf) * xh_s[ro];
                float m = m_s[ro];
                float xtv = xt_s[ro];
                float xi = m * xtv + (1.f - m) * xc;
                float nx = __shfl_down(xi, 8);
                if (o + 1 >= 89) nx = 0.f;
                if (o < 89) {
                    out[XIMP_OFF + (b * T_ + t) * D_ + o] = xi;
                    diff_s[o] = fabsf(xtv - xc) * m;
                }
                if ((oo & 1) == 0 && o < 89) ximp_h[o >> 1] = packh2(xi, nx);
            }
        } else if (tid >= 768 && tid < 857 && t + 1 < T_) {
            int o = tid - 768;
            float dv = deltas[(b * T_ + t + 1) * D_ + o];
            float gxv = __expf(-fmaxf(dv * dxw + dxb, 0.f));
            float nd = __shfl_down(dv, 1);
            float ng = __shfl_down(gxv, 1);
            if (o + 1 >= 89) { nd = 0.f; ng = 0.f; }
            if ((o & 1) == 0) { dt_h[o >> 1] = packh2(dv, nd); gx_h[o >> 1] = packh2(gxv, ng); }
        }
        __syncthreads();
        // ---- P4: gi_x = W_ih[:, :89] . ximp (48 chunks).
        for (int c = wave; c < 48; c += 16) {
            int o = c * 8 + oo;
            float acc = 0.f;
            DOT96H(wihx_h + o * 48, ximp_h, acc);
            acc += __shfl_xor(acc, 1); acc += __shfl_xor(acc, 2); acc += __shfl_xor(acc, 4);
            if (jj == 0) gis[o] += acc;
        }
        __syncthreads();
        // ---- P5: GRU+gamma(t+1)+hdec | xt/m prefetch | loss (wave 15)
        if (tid < 128) {
            float r = sigm(gis[tid] + ghs[tid]);
            float z = sigm(gis[128 + tid] + ghs[128 + tid]);
            float g = tanhf(gis[256 + tid] + r * ghs[256 + tid]);
            float hn = (1.f - z) * g + z * h_s[tid];
            out[HID_OFF + (size_t)(b * T_ + t) * H_ + tid] = hn;
            float hd = hn;
            if (t + 1 < T_) {
                const uint_t* wr = wdh_l + tid * 49;
                float acc = 0.f;
                #pragma unroll
                for (int j = 0; j < 45; ++j) acc = dot2h(wr[j], dt_h[j], acc);
                hd = hn * __expf(-fmaxf(acc + b_dh[tid], 0.f));
            }
            h_s[tid] = hd;
            float nx = __shfl_down(hd, 1);
            if ((tid & 1) == 0) h_h[tid >> 1] = packh2(hd, nx);
        } else if (tid >= 960) {
            int l = tid - 960;
            float s = diff_s[l] + ((l < 25) ? diff_s[64 + l] : 0.f);
            s = wave_sum64(s);
            if (l == 0) num_part[t * B_ + b] = s;
        } else if (t + 1 < T_) {
            int nb = (b * T_ + t + 1) * D_;
            if (tid < 217) xt_s[tid - 128] = x[nb + tid - 128];
            else if (tid >= 256 && tid < 345) {
                int o = tid - 256;
                float mv = mask[nb + o];
                m_s[o] = mv;
                float nx = __shfl_down(mv, 1);
                if (o + 1 >= 89) nx = 0.f;
                if ((o & 1) == 0) m_h[o >> 1] = packh2(mv, nx);
            }
        }
        __syncthreads();
    }
    // classifier (h_s holds final hn: gamma skipped at t = T-1)
    if (tid < 64) {
        float p = h_s[tid] * W_cls[tid] + h_s[tid + 64] * W_cls[tid + 64];
        p = wave_sum64(p);
        if (tid == 0) {
            float y = p + b_cls[0];
            out[Y_OFF + b] = y;
            out[YS_OFF + b] = 1.f / (1.f + __expf(-y));
        }
    }
}

// ---------------- final loss reduction
__global__ void k_loss(const float* __restrict__ num_part, const float* __restrict__ den,
                       float* __restrict__ out) {
    int tid = threadIdx.x;
    float v = 0.f;
    if (tid < T_) {
        float s = 0.f;
        const float* np_ = num_part + tid * B_;
        for (int b = 0; b < B_; ++b) s += np_[b];
        v = s / (den[tid] + 1e-5f);
    }
    v = wave_sum64(v);
    if (tid == 0) out[LOSS_OFF] = v;
}

extern "C" void kernel_launch(void* const* d_in, const int* in_sizes, int n_in,
                              void* d_out, int out_size, void* d_ws, size_t ws_size,
                              hipStream_t stream) {
    const float* x        = (const float*)d_in[0];
    const float* mask     = (const float*)d_in[1];
    const float* deltas   = (const float*)d_in[2];
    const float* last_obs = (const float*)d_in[3];
    const float* medians  = (const float*)d_in[4];
    const float* W_dh  = (const float*)d_in[5];
    const float* b_dh  = (const float*)d_in[6];
    const float* W_dx  = (const float*)d_in[7];
    const float* b_dx  = (const float*)d_in[8];
    const float* W_hist= (const float*)d_in[9];
    const float* b_hist= (const float*)d_in[10];
    const float* W_feat= (const float*)d_in[11];
    const float* b_feat= (const float*)d_in[12];
    const float* W_wc  = (const float*)d_in[13];
    const float* b_wc  = (const float*)d_in[14];
    const float* W_wo  = (const float*)d_in[15];
    const float* b_wo  = (const float*)d_in[16];
    const float* W_cls = (const float*)d_in[17];
    const float* b_cls = (const float*)d_in[18];
    const float* W_ih  = (const float*)d_in[19];
    const float* W_hh  = (const float*)d_in[20];
    const float* b_ih  = (const float*)d_in[21];
    const float* b_hh  = (const float*)d_in[22];
    const float* W_inp = (const float*)d_in[23];
    const float* b_inp = (const float*)d_in[24];
    const float* W_op1 = (const float*)d_in[25];
    const float* b_op1 = (const float*)d_in[26];
    const float* W_op2 = (const float*)d_in[27];
    const float* b_op2 = (const float*)d_in[28];
    const float* attn_in_w  = (const float*)d_in[29];
    const float* attn_in_b  = (const float*)d_in[30];
    const float* attn_out_w = (const float*)d_in[31];
    const float* attn_out_b = (const float*)d_in[32];
    const float* ln1_g = (const float*)d_in[33];
    const float* ln1_b = (const float*)d_in[34];
    const float* ln2_g = (const float*)d_in[35];
    const float* ln2_b = (const float*)d_in[36];
    const float* ff1_w = (const float*)d_in[37];
    const float* ff1_b = (const float*)d_in[38];
    const float* ff2_w = (const float*)d_in[39];
    const float* ff2_b = (const float*)d_in[40];

    float* out = (float*)d_out;
    float* ws = (float*)d_ws;

    float* data  = ws;                                   // B*96*64
    float* qb    = data  + (size_t)B_ * N2T * C_;
    float* kb    = qb    + (size_t)N2T * NH_ * B_ * HD_;
    float* vb    = kb    + (size_t)N2T * NH_ * B_ * HD_;
    float* attnO = vb    + (size_t)N2T * NH_ * B_ * HD_;
    float* val   = attnO + (size_t)B_ * N2T * C_;        // B*96*128
    float* h0    = val   + (size_t)B_ * N2T * H_;
    float* den   = h0    + (size_t)B_ * H_;
    float* nump  = den   + 64;
    float* W_woT = nump  + T_ * B_;
    float* W_inpT= W_woT + 7921;
    float* ain_T = W_inpT + 5696;
    float* aout_T= ain_T + 12288;
    float* ff1_T = aout_T + 4096;
    float* ff2_T = ff1_T + 4096;
    float* op1_T = ff2_T + 4096;
    uint_t* wdh_h   = (uint_t*)(op1_T + 8192);
    uint_t* whist_h = wdh_h + 6144;
    uint_t* wihx_h  = whist_h + 5696;
    uint_t* wihm_h  = wihx_h + 18432;
    uint_t* whh_h   = wihm_h + 18432;

    k_wprep<<<468, 256, 0, stream>>>(W_wo, W_inp, attn_in_w, attn_out_w, ff1_w, ff2_w, W_op1,
                                     W_woT, W_inpT, ain_T, aout_T, ff1_T, ff2_T, op1_T,
                                     W_dh, W_hist, W_ih, W_hh,
                                     wdh_h, whist_h, wihx_h, wihm_h, whh_h);
    k_phaseA<<<B_ * T_, 128, 0, stream>>>(last_obs, deltas, medians, W_woT, b_wo, W_inpT, b_inp,
                                          ain_T, attn_in_b, data, qb, kb, vb);
    k_attn<<<N2T * NH_, 256, 0, stream>>>(qb, kb, vb, attnO);
    k_transform<<<B_ * N2T, 64, 0, stream>>>(data, attnO, aout_T, attn_out_b,
                                             ln1_g, ln1_b, ff1_T, ff1_b, ff2_T, ff2_b,
                                             ln2_g, ln2_b, op1_T, b_op1, val);
    k_reduce_h0<<<B_, H_, 0, stream>>>(val, W_op2, b_op2, h0);
    k_den<<<T_, 256, 0, stream>>>(mask, den);
    k_scan<<<B_, 1024, 0, stream>>>(x, mask, deltas,
                                    wdh_h, b_dh, W_dx, b_dx, whist_h, b_hist, W_feat, b_feat,
                                    W_wc, b_wc, wihx_h, wihm_h, whh_h, b_ih, b_hh, W_cls, b_cls,
                                    h0, out, nump);
    k_loss<<<1, 64, 0, stream>>>(nump, den, out);
}